// Round 1
// 354.560 us; speedup vs baseline: 1.0004x; 1.0004x over previous
//
#include <hip/hip_runtime.h>

// Polar encoder: N=1024, K=512, BATCH=65536.
// R9: R8 structure (1 row/wave, ballot pack, nt stores, inv in d_ws) plus:
//  - per-round activity mask computed generically in build_inv (bit c set iff
//    round c has any info bit); encode skips inactive rounds via a uniform
//    scalar branch. For the reference frozen layout (frozen = 0..511) this
//    halves the gather/ballot chain: 16 -> 8 active rounds.
//  - nontemporal loads for u (zero reuse; poison flushes L3 every iter anyway).

#define PN     1024
#define PK     512
#define PBATCH 65536
#define ROUNDS 16   // PN / 64

typedef float vf4 __attribute__((ext_vector_type(4)));

__global__ __launch_bounds__(256) void build_inv_kernel(
    const int* __restrict__ info_pos, int* __restrict__ inv)
{
    const int tid = threadIdx.x;
    #pragma unroll
    for (int i = tid; i < PN; i += 256) inv[i] = -1;
    if (tid == 0) inv[PN] = 0;          // round-activity mask accumulator
    __syncthreads();
    #pragma unroll
    for (int k = tid; k < PK; k += 256) inv[info_pos[k]] = k;
    __syncthreads();
    // bit c of inv[PN] set iff round c (positions 64c..64c+63) has info bits
    if (tid < ROUNDS) {
        int any = 0;
        for (int i = 0; i < 64; ++i) any |= (inv[tid * 64 + i] >= 0) ? 1 : 0;
        if (any) atomicOr(&inv[PN], 1 << tid);
    }
}

__device__ __forceinline__ void encode_row(
    const float* __restrict__ u,
    const int*   __restrict__ inv,     // generic pointer (LDS or global ok)
    float*       __restrict__ srow,    // this wave's 512-float staging
    vf4*         __restrict__ out4,
    int lane, unsigned row, unsigned rmask)
{
    // --- stage 1 row (512 floats = 128 float4, 2 per lane, coalesced, nt)
    const vf4* u4 = (const vf4*)(u + (size_t)row * PK);
    const vf4 a0 = __builtin_nontemporal_load(u4 + lane);
    const vf4 a1 = __builtin_nontemporal_load(u4 + 64 + lane);
    vf4* s4 = (vf4*)srow;
    s4[lane]      = a0;
    s4[64 + lane] = a1;   // wave-private: no barrier

    const int l31 = lane & 31;

    // --- gather + pack: round c covers positions 64c..64c+63 -> words 2c,2c+1
    // rounds with no info bits (rmask bit clear) contribute word = 0: skip.
    unsigned int word = 0;
    #pragma unroll
    for (int c = 0; c < ROUNDS; ++c) {
        if (rmask & (1u << c)) {        // uniform (SGPR) branch
            const int   iv  = inv[c * 64 + lane];
            const float v   = srow[iv & (PK - 1)];
            const bool  bit = (iv >= 0) && (v != 0.0f);
            const unsigned long long m = __ballot(bit);
            const unsigned int sel =
                (l31 & 1) ? (unsigned int)(m >> 32) : (unsigned int)m;
            if ((l31 >> 1) == c) word = sel;   // lane l31 keeps word l31
        }
    }

    // --- butterfly stages 0..4 (in-word)
    word ^= (word >> 1)  & 0x55555555u;
    word ^= (word >> 2)  & 0x33333333u;
    word ^= (word >> 4)  & 0x0F0F0F0Fu;
    word ^= (word >> 8)  & 0x00FF00FFu;
    word ^= (word >> 16) & 0x0000FFFFu;

    // --- butterfly stages 5..9 (cross-lane; both 32-lane halves mirror)
    #pragma unroll
    for (int off = 1; off <= 16; off <<= 1) {
        const unsigned int partner =
            (unsigned int)__shfl_xor((int)word, off, 64);
        if ((l31 & off) == 0) word ^= partner;
    }

    // --- expand + nontemporal coalesced stores: 256 float4 per row, 4 iters
    const unsigned base = row * (PN / 4);   // row * 256
    #pragma unroll
    for (int j = 0; j < 4; ++j) {
        const int f   = j * 64 + lane;          // 0..255
        const int src = f >> 3;                 // word index 0..31 (lane 0..31)
        const unsigned int b   = (unsigned int)__shfl((int)word, src, 64);
        const unsigned int nib = (b >> ((f & 7) * 4)) & 0xFu;
        vf4 v;
        v.x = (nib & 1u) ? 1.0f : 0.0f;
        v.y = (nib & 2u) ? 1.0f : 0.0f;
        v.z = (nib & 4u) ? 1.0f : 0.0f;
        v.w = (nib & 8u) ? 1.0f : 0.0f;
        __builtin_nontemporal_store(v, out4 + base + f);
    }
}

__global__ __launch_bounds__(256) void polar_encode_kernel(
    const float* __restrict__ u,
    const int*   __restrict__ ginv,   // [PN+1] prebuilt in d_ws (last = rmask)
    vf4*         __restrict__ out4)
{
    __shared__ float su[4][PK];       // 8 KB: per-wave 1-row staging
    const int tid  = threadIdx.x;
    const int lane = tid & 63;
    const int wave = tid >> 6;
    const unsigned row = blockIdx.x * 4u + wave;
    const unsigned rmask =
        (unsigned)__builtin_amdgcn_readfirstlane(ginv[PN]);
    encode_row(u, ginv, su[wave], out4, lane, row, rmask);
}

// Fallback (ws too small): inv + mask built in LDS per block.
__global__ __launch_bounds__(256) void polar_fused_kernel(
    const float* __restrict__ u,
    const int*   __restrict__ info_pos,
    vf4*         __restrict__ out4)
{
    __shared__ int   inv[PN];
    __shared__ int   smask;
    __shared__ float su[4][PK];
    const int tid = threadIdx.x;
    #pragma unroll
    for (int i = tid; i < PN; i += 256) inv[i] = -1;
    if (tid == 0) smask = 0;
    __syncthreads();
    #pragma unroll
    for (int k = tid; k < PK; k += 256) inv[info_pos[k]] = k;
    __syncthreads();
    if (tid < ROUNDS) {
        int any = 0;
        for (int i = 0; i < 64; ++i) any |= (inv[tid * 64 + i] >= 0) ? 1 : 0;
        if (any) atomicOr(&smask, 1 << tid);
    }
    __syncthreads();

    const int lane = tid & 63;
    const int wave = tid >> 6;
    const unsigned row = blockIdx.x * 4u + wave;
    const unsigned rmask =
        (unsigned)__builtin_amdgcn_readfirstlane(smask);
    encode_row(u, inv, su[wave], out4, lane, row, rmask);
}

extern "C" void kernel_launch(void* const* d_in, const int* in_sizes, int n_in,
                              void* d_out, int out_size, void* d_ws, size_t ws_size,
                              hipStream_t stream) {
    const float* u        = (const float*)d_in[0];
    const int*   info_pos = (const int*)d_in[1];
    vf4* out4 = (vf4*)d_out;

    if (ws_size >= (size_t)(PN + 1) * sizeof(int)) {
        int* inv = (int*)d_ws;
        build_inv_kernel<<<1, 256, 0, stream>>>(info_pos, inv);
        polar_encode_kernel<<<PBATCH / 4, 256, 0, stream>>>(u, inv, out4);
    } else {
        polar_fused_kernel<<<PBATCH / 4, 256, 0, stream>>>(u, info_pos, out4);
    }
}